// Round 11
// baseline (763.887 us; speedup 1.0000x reference)
//
#include <hip/hip_runtime.h>
#include <math.h>

#define NEXP 32
#define NTOK 256
#define DIMD 768
#define DHID 2048
#define DBOT 256
#define DOUT 768
#define NSLOT 512

// ---------------- gate: logits -> top2 -> weights; init y with bl; zero z and A ----------------
__global__ __launch_bounds__(64) void gate_kernel(
    const float* __restrict__ x, const float* __restrict__ gw,
    const float* __restrict__ bl, float* __restrict__ y,
    int* __restrict__ topk_idx, float* __restrict__ topk_w,
    float* __restrict__ z, float* __restrict__ A) {
  const int n = blockIdx.x;
  const int l = threadIdx.x;
  {  // zero z slice (512 f) and A slice (4096 f) for this block
    const float4 zv = {0.f, 0.f, 0.f, 0.f};
    float4* zp = (float4*)(z + n * 512 + l * 8);
    zp[0] = zv; zp[1] = zv;
    float4* ap = (float4*)(A + (size_t)n * 4096 + l * 64);
#pragma unroll
    for (int j = 0; j < 16; j++) ap[j] = zv;
  }
  const float* xr = x + n * DIMD;
  float xs[12];
#pragma unroll
  for (int j = 0; j < 12; j++) xs[j] = xr[l + 64 * j];
  float logit[NEXP];
#pragma unroll
  for (int e = 0; e < NEXP; e++) {
    const float* g = gw + e * DIMD;
    float p = 0.f;
#pragma unroll
    for (int j = 0; j < 12; j++) p = fmaf(xs[j], g[l + 64 * j], p);
#pragma unroll
    for (int m = 1; m < 64; m <<= 1) p += __shfl_xor(p, m);
    logit[e] = p;
  }
  int i0 = 0; float m0 = logit[0];
#pragma unroll
  for (int e = 1; e < NEXP; e++) { if (logit[e] > m0) { m0 = logit[e]; i0 = e; } }
  int i1 = -1; float m1 = -3.4e38f;
#pragma unroll
  for (int e = 0; e < NEXP; e++) { if (e != i0 && logit[e] > m1) { m1 = logit[e]; i1 = e; } }
  const float e1 = expf(m1 - m0);
  const float w0 = 1.f / (1.f + e1);
  const float w1 = e1 * w0;
  if (l == 0) {
    topk_idx[2 * n] = i0; topk_idx[2 * n + 1] = i1;
    topk_w[2 * n] = w0;  topk_w[2 * n + 1] = w1;
  }
  const float* bl0 = bl + i0 * DOUT;
  const float* bl1 = bl + i1 * DOUT;
#pragma unroll
  for (int j = 0; j < 12; j++) {
    const int o = l + 64 * j;
    y[n * DOUT + o] = fmaf(w0, bl0[o], w1 * bl1[o]);
  }
}

// ---------------- build compact per-expert token lists (+ slot->expert map) ----------------
__global__ __launch_bounds__(256) void build_lists(
    const int* __restrict__ topk_idx, const float* __restrict__ topk_w,
    int* __restrict__ counts, int* __restrict__ offsets,
    int* __restrict__ tok_list, float* __restrict__ tok_wt,
    int* __restrict__ slot_expert) {
  __shared__ int cnt[NEXP], base[NEXP], fill[NEXP];
  const int t = threadIdx.x;
  if (t < NEXP) { cnt[t] = 0; fill[t] = 0; }
  __syncthreads();
  const int e0 = topk_idx[2 * t], e1 = topk_idx[2 * t + 1];
  atomicAdd(&cnt[e0], 1);
  atomicAdd(&cnt[e1], 1);
  __syncthreads();
  if (t == 0) { int s = 0; for (int i = 0; i < NEXP; i++) { base[i] = s; s += cnt[i]; } }
  __syncthreads();
  const int p0 = atomicAdd(&fill[e0], 1);
  tok_list[base[e0] + p0] = t; tok_wt[base[e0] + p0] = topk_w[2 * t];
  slot_expert[base[e0] + p0] = e0;
  const int p1 = atomicAdd(&fill[e1], 1);
  tok_list[base[e1] + p1] = t; tok_wt[base[e1] + p1] = topk_w[2 * t + 1];
  slot_expert[base[e1] + p1] = e1;
  if (t < NEXP) { counts[t] = cnt[t]; offsets[t] = base[t]; }
}

__device__ __forceinline__ float gelu_f(float v) {
  return 0.5f * v * (1.f + erff(v * 0.70710678118654752f));
}

// ---------------- bias + gelu pass: B = gelu(A + bias[e]); A = 0 ----------------
__global__ __launch_bounds__(256) void gelu_pass(
    const float* __restrict__ A, const float* __restrict__ bias,
    float* __restrict__ Bout, float* __restrict__ Azero,
    const int* __restrict__ slot_expert) {
  const int slot = blockIdx.x;
  const int e = slot_expert[slot];
  const int c0 = threadIdx.x * 8;
  const float* ap = A + (size_t)slot * DHID + c0;
  const float* bp = bias + (size_t)e * DHID + c0;
  float* op = Bout + (size_t)slot * DHID + c0;
  float* zp = Azero + (size_t)slot * DHID + c0;
  const float4 zz = {0.f, 0.f, 0.f, 0.f};
#pragma unroll
  for (int j = 0; j < 8; j += 4) {
    const float4 a = *(const float4*)(ap + j);
    const float4 b = *(const float4*)(bp + j);
    float4 o;
    o.x = gelu_f(a.x + b.x); o.y = gelu_f(a.y + b.y);
    o.z = gelu_f(a.z + b.z); o.w = gelu_f(a.w + b.w);
    *(float4*)(op + j) = o;
    *(float4*)(zp + j) = zz;
  }
}

#define FMA4(A, XS, WV) \
  A.x = fmaf(XS, WV.x, A.x); A.y = fmaf(XS, WV.y, A.y); \
  A.z = fmaf(XS, WV.z, A.z); A.w = fmaf(XS, WV.w, A.w)

// ---------------- generic expert FF K-tile (micro-tiled) ----------------
// Block 512 thr = 8 waves; wave tg owns tokens tg*4..tg*4+3; lane cg owns CPT cols.
// Per K-row per wave: ONE broadcast ds_read_b128 (4 tokens' act) + CPT-col
// coalesced weight load + 4*CPT FMA  ->  LDS pipe no longer the bottleneck
// (previous design: 8 b128/row/wave = LDS-bound at ~2.2 TB/s, R1-R10).
// KR = 256 rows per K-tile; rotating 4-slot weight prefetch, distance 2 (R8-proven).
// MODE 0: x(gather) @ W1 -> A (atomic; gelu later)   CPT=8
// MODE 1: B @ W2 -> A (atomic)                       CPT=8
// MODE 2: B @ W3 -> z (atomic, pre-zeroed)           CPT=4
// MODE 3: (z+b3) @ Wl -> y (atomic weighted scatter) CPT=4
template <int MODE, int CPT>
__global__ __launch_bounds__(512, 2) void ff_kernel(
    const float* __restrict__ Ain, const float* __restrict__ W,
    const float* __restrict__ Bias, float* __restrict__ Out,
    const int* __restrict__ offsets, const int* __restrict__ counts,
    const int* __restrict__ tok_list, const float* __restrict__ tok_wt,
    int KTOT, int NCT, int INS, int coltiles) {
  __shared__ float act_t[256 * 32];   // 32 KB, [k][tok] transposed
  const int tid = threadIdx.x;
  const int tg  = tid >> 6;          // wave = 4-token group
  const int cg  = tid & 63;          // col group within tile
  const int e   = blockIdx.y;
  const int ct  = blockIdx.x % coltiles;
  const int kb  = blockIdx.x / coltiles;
  const int cnt = counts[e];
  const int off = offsets[e];
  const int col = ct * (64 * CPT) + cg * CPT;
  const float* Wcol = W + ((size_t)e * KTOT + (size_t)kb * 256) * NCT + col;
  const float* bfold = (MODE == 3) ? (Bias + (size_t)e * KTOT + kb * 256) : nullptr;

  for (int tc0 = 0; tc0 < cnt; tc0 += 32) {
    const int tcn = min(32, cnt - tc0);
    // ---- stage act_t[256][32]: thread (tok=tid&31, kk=tid>>5) stages 16 rows ----
    {
      const int tok = tid & 31;
      const int kk  = tid >> 5;      // 0..15
      float v[16];
      if (tok < tcn) {
        const int slot = off + tc0 + tok;
        const int row  = (MODE == 0) ? tok_list[slot] : slot;
        const float* src = Ain + (size_t)row * INS + kb * 256 + kk * 16;
#pragma unroll
        for (int j = 0; j < 16; j += 4) {
          float4 q = *(const float4*)(src + j);
          if (MODE == 3) {
            const float4 b = *(const float4*)(bfold + kk * 16 + j);
            q.x += b.x; q.y += b.y; q.z += b.z; q.w += b.w;
          }
          v[j] = q.x; v[j + 1] = q.y; v[j + 2] = q.z; v[j + 3] = q.w;
        }
      } else {
#pragma unroll
        for (int j = 0; j < 16; j++) v[j] = 0.f;
      }
#pragma unroll
      for (int j = 0; j < 16; j++) act_t[(kk * 16 + j) * 32 + tok] = v[j];
    }
    __syncthreads();

    // ---- K-loop: 256 rows, rotating depth-2 weight prefetch ----
    float4 acc0[4], acc1[4];
#pragma unroll
    for (int t = 0; t < 4; t++) {
      acc0[t] = {0.f, 0.f, 0.f, 0.f};
      acc1[t] = {0.f, 0.f, 0.f, 0.f};
    }
    float4 wa0[4], wa1[4];
    wa0[0] = *(const float4*)(Wcol);
    wa0[1] = *(const float4*)(Wcol + NCT);
    if (CPT == 8) {
      wa1[0] = *(const float4*)(Wcol + 4);
      wa1[1] = *(const float4*)(Wcol + NCT + 4);
    }
#pragma unroll 4
    for (int r = 0; r < 256; ++r) {
      const int cur = r & 3;
      const int nxt = (r + 2) & 3;
      const int rp  = min(r + 2, 255);
      wa0[nxt] = *(const float4*)(Wcol + (size_t)rp * NCT);
      if (CPT == 8) wa1[nxt] = *(const float4*)(Wcol + (size_t)rp * NCT + 4);
      const float4 xv = *(const float4*)(&act_t[r * 32 + tg * 4]);  // broadcast
      FMA4(acc0[0], xv.x, wa0[cur]);
      FMA4(acc0[1], xv.y, wa0[cur]);
      FMA4(acc0[2], xv.z, wa0[cur]);
      FMA4(acc0[3], xv.w, wa0[cur]);
      if (CPT == 8) {
        FMA4(acc1[0], xv.x, wa1[cur]);
        FMA4(acc1[1], xv.y, wa1[cur]);
        FMA4(acc1[2], xv.z, wa1[cur]);
        FMA4(acc1[3], xv.w, wa1[cur]);
      }
    }
    __syncthreads();   // compute done before next chunk restages act_t

    // ---- emit: 4 tokens x CPT cols, fully static acc indexing ----
#pragma unroll
    for (int tt = 0; tt < 4; tt++) {
      if (tg * 4 + tt < tcn) {
        const int slot = off + tc0 + tg * 4 + tt;
        if (MODE <= 2) {
          float* o = Out + (size_t)slot * NCT + col;
          atomicAdd(o + 0, acc0[tt].x);
          atomicAdd(o + 1, acc0[tt].y);
          atomicAdd(o + 2, acc0[tt].z);
          atomicAdd(o + 3, acc0[tt].w);
          if (CPT == 8) {
            atomicAdd(o + 4, acc1[tt].x);
            atomicAdd(o + 5, acc1[tt].y);
            atomicAdd(o + 6, acc1[tt].z);
            atomicAdd(o + 7, acc1[tt].w);
          }
        } else {
          const int trow = tok_list[slot];
          const float wgt = tok_wt[slot];
          float* o = Out + (size_t)trow * DOUT + col;
          atomicAdd(o + 0, wgt * acc0[tt].x);
          atomicAdd(o + 1, wgt * acc0[tt].y);
          atomicAdd(o + 2, wgt * acc0[tt].z);
          atomicAdd(o + 3, wgt * acc0[tt].w);
        }
      }
    }
  }
}

extern "C" void kernel_launch(void* const* d_in, const int* in_sizes, int n_in,
                              void* d_out, int out_size, void* d_ws, size_t ws_size,
                              hipStream_t stream) {
  const float* x  = (const float*)d_in[0];
  const float* gw = (const float*)d_in[1];
  const float* W1 = (const float*)d_in[2];
  const float* b1 = (const float*)d_in[3];
  const float* W2 = (const float*)d_in[4];
  const float* b2 = (const float*)d_in[5];
  const float* W3 = (const float*)d_in[6];
  const float* b3 = (const float*)d_in[7];
  const float* Wl = (const float*)d_in[8];
  const float* bl = (const float*)d_in[9];
  float* y  = (float*)d_out;
  float* ws = (float*)d_ws;

  float* topk_w   = ws;                    // 512 f
  int*   topk_idx = (int*)(ws + 512);      // 512 i
  int*   counts   = (int*)(ws + 1024);     // 32 i
  int*   offsets  = (int*)(ws + 1056);     // 32 i
  int*   tok_list = (int*)(ws + 1088);     // 512 i
  float* tok_wt   = ws + 1600;             // 512 f
  int*   slot_exp = (int*)(ws + 2112);     // 512 i
  float* A = ws + 4096;                    // 512*2048 accumulator (pre-gelu)
  float* B = A + (size_t)NSLOT * DHID;     // 512*2048 activations (post-gelu)
  float* z = B + (size_t)NSLOT * DHID;     // 512*256

  gate_kernel<<<NTOK, 64, 0, stream>>>(x, gw, bl, y, topk_idx, topk_w, z, A);
  build_lists<<<1, 256, 0, stream>>>(topk_idx, topk_w, counts, offsets, tok_list, tok_wt, slot_exp);
  // L1: x @ W1 -> A   (4 coltiles x 3 Ktiles x 32 experts = 384 blocks)
  ff_kernel<0, 8><<<dim3(12, 32), 512, 0, stream>>>(x, W1, nullptr, A, offsets, counts,
                                                    tok_list, tok_wt, DIMD, DHID, DIMD, 4);
  gelu_pass<<<NSLOT, 256, 0, stream>>>(A, b1, B, A, slot_exp);   // B = gelu(A+b1); A = 0
  // L2: B @ W2 -> A   (4 coltiles x 8 Ktiles x 32 experts = 1024 blocks)
  ff_kernel<1, 8><<<dim3(32, 32), 512, 0, stream>>>(B, W2, nullptr, A, offsets, counts,
                                                    tok_list, tok_wt, DHID, DHID, DHID, 4);
  gelu_pass<<<NSLOT, 256, 0, stream>>>(A, b2, B, A, slot_exp);   // B = gelu(A+b2); A = 0
  // L3: B @ W3 -> z   (1 coltile x 8 Ktiles x 32 experts = 256 blocks)
  ff_kernel<2, 4><<<dim3(8, 32), 512, 0, stream>>>(B, W3, nullptr, z, offsets, counts,
                                                   tok_list, tok_wt, DHID, DBOT, DHID, 1);
  // L4: (z+b3) @ Wl -> y  (3 coltiles x 1 Ktile x 32 experts = 96 blocks)
  ff_kernel<3, 4><<<dim3(3, 32), 512, 0, stream>>>(z, Wl, b3, y, offsets, counts,
                                                   tok_list, tok_wt, DBOT, DOUT, DBOT, 3);
}

// Round 12
// 444.916 us; speedup vs baseline: 1.7169x; 1.7169x over previous
//
#include <hip/hip_runtime.h>
#include <math.h>

#define NEXP 32
#define NTOK 256
#define DIMD 768
#define DHID 2048
#define DBOT 256
#define DOUT 768
#define NSLOT 512

// ---------------- gate: logits -> top2 -> normalized weights ----------------
__global__ __launch_bounds__(64) void gate_kernel(
    const float* __restrict__ x, const float* __restrict__ gw,
    int* __restrict__ topk_idx, float* __restrict__ topk_w) {
  const int n = blockIdx.x;
  const int l = threadIdx.x;
  const float* xr = x + n * DIMD;
  float xs[12];
#pragma unroll
  for (int j = 0; j < 12; j++) xs[j] = xr[l + 64 * j];
  float logit[NEXP];
#pragma unroll
  for (int e = 0; e < NEXP; e++) {
    const float* g = gw + e * DIMD;
    float p = 0.f;
#pragma unroll
    for (int j = 0; j < 12; j++) p = fmaf(xs[j], g[l + 64 * j], p);
#pragma unroll
    for (int m = 1; m < 64; m <<= 1) p += __shfl_xor(p, m);
    logit[e] = p;
  }
  int i0 = 0; float m0 = logit[0];
#pragma unroll
  for (int e = 1; e < NEXP; e++) { if (logit[e] > m0) { m0 = logit[e]; i0 = e; } }
  int i1 = -1; float m1 = -3.4e38f;
#pragma unroll
  for (int e = 0; e < NEXP; e++) { if (e != i0 && logit[e] > m1) { m1 = logit[e]; i1 = e; } }
  const float e1 = expf(m1 - m0);
  const float w0 = 1.f / (1.f + e1);
  const float w1 = e1 * w0;
  if (l == 0) {
    topk_idx[2 * n] = i0; topk_idx[2 * n + 1] = i1;
    topk_w[2 * n] = w0;  topk_w[2 * n + 1] = w1;
  }
}

// ---------------- build compact per-expert token lists + token->slot map ----------------
__global__ __launch_bounds__(256) void build_lists(
    const int* __restrict__ topk_idx,
    int* __restrict__ counts, int* __restrict__ offsets,
    int* __restrict__ tok_list, int* __restrict__ tok2slot) {
  __shared__ int cnt[NEXP], base[NEXP], fill[NEXP];
  const int t = threadIdx.x;
  if (t < NEXP) { cnt[t] = 0; fill[t] = 0; }
  __syncthreads();
  const int e0 = topk_idx[2 * t], e1 = topk_idx[2 * t + 1];
  atomicAdd(&cnt[e0], 1);
  atomicAdd(&cnt[e1], 1);
  __syncthreads();
  if (t == 0) { int s = 0; for (int i = 0; i < NEXP; i++) { base[i] = s; s += cnt[i]; } }
  __syncthreads();
  const int p0 = atomicAdd(&fill[e0], 1);
  tok_list[base[e0] + p0] = t; tok2slot[2 * t] = base[e0] + p0;
  const int p1 = atomicAdd(&fill[e1], 1);
  tok_list[base[e1] + p1] = t; tok2slot[2 * t + 1] = base[e1] + p1;
  if (t < NEXP) { counts[t] = cnt[t]; offsets[t] = base[t]; }
}

__device__ __forceinline__ float gelu_f(float v) {
  return 0.5f * v * (1.f + erff(v * 0.70710678118654752f));
}

#define FMA4(A, XS, WV) \
  A.x = fmaf(XS, WV.x, A.x); A.y = fmaf(XS, WV.y, A.y); \
  A.z = fmaf(XS, WV.z, A.z); A.w = fmaf(XS, WV.w, A.w)

// ---------------- expert FF layer, NO ATOMICS (full-K per output element) ----------------
// Block 512 thr = 8 waves; wave tg = tokens tg*4..+3, lane cg = 4 cols.
// Per row per wave: 1 broadcast ds_read_b128 + 1 coalesced float4 weight load + 16 FMA.
// K walked in 256-row LDS sections; rotating 8-slot float4 weight prefetch, distance 4
// (64 B/lane in flight -> 32 KB/CU). Direct stores only:
// MODE 0: B1 = gelu(x(gather) @ W1 + b1)          grid (8,32), K=768
// MODE 1: B2 = gelu(B1 @ W2 + b2)                 grid (8,32), K=2048
// MODE 2: zpart[kb] = B2 @ W3 (256-row K-slice)   grid (8,32), K=256/block
// MODE 3: OutS = (sum_k zpart[k] + b3) @ Wl       grid (3,32), K=256
template <int MODE>
__global__ __launch_bounds__(512, 2) void ff_kernel(
    const float* __restrict__ Ain, const float* __restrict__ W,
    const float* __restrict__ Bias, float* __restrict__ Out,
    const float* __restrict__ zpart,
    const int* __restrict__ offsets, const int* __restrict__ counts,
    const int* __restrict__ tok_list) {
  constexpr int KBLK  = (MODE == 0) ? 768 : (MODE == 1) ? 2048 : 256;  // K rows per block
  constexpr int NCT   = (MODE <= 1) ? 2048 : (MODE == 2) ? 256 : 768;
  constexpr int INS   = (MODE == 0) ? DIMD : DHID;
  constexpr int NSEC  = KBLK / 256;
  constexpr int COLT  = NCT / 256;
  constexpr int KFULL = (MODE == 2) ? DHID : KBLK;   // W's K extent
  __shared__ float act_t[256 * 32];   // 32 KB, [k][tok] transposed
  const int tid = threadIdx.x;
  const int tg  = tid >> 6;
  const int cg  = tid & 63;
  const int e   = blockIdx.y;
  const int ct  = blockIdx.x % COLT;
  const int kb  = blockIdx.x / COLT;   // >0 only for MODE 2
  const int cnt = counts[e];
  const int off = offsets[e];
  const int col = ct * 256 + cg * 4;
  const float* Wcol = W + ((size_t)e * KFULL + kb * 256) * NCT + col;
  const int tok = tid & 31;
  const int kk  = tid >> 5;

  for (int tc0 = 0; tc0 < cnt; tc0 += 32) {
    const int tcn = min(32, cnt - tc0);
    float4 acc[4];
#pragma unroll
    for (int t = 0; t < 4; t++) acc[t] = {0.f, 0.f, 0.f, 0.f};
    float4 wbuf[8];
#pragma unroll
    for (int d = 0; d < 4; d++) wbuf[d] = *(const float4*)(Wcol + (size_t)d * NCT);

    for (int s = 0; s < NSEC; s++) {
      __syncthreads();   // previous section's compute done before restage
      {  // ---- stage act_t[256][32]: thread (tok, kk) covers 16 rows of one token ----
        float v[16];
        if (tok < tcn) {
          const int slot = off + tc0 + tok;
          if (MODE == 3) {
            const float* bs = Bias + (size_t)e * DBOT + kk * 16;
#pragma unroll
            for (int j = 0; j < 16; j += 4) {
              float4 q = *(const float4*)(bs + j);
#pragma unroll
              for (int k = 0; k < 8; k++) {
                const float4 p = *(const float4*)(
                    zpart + ((size_t)k * NSLOT + slot) * DBOT + kk * 16 + j);
                q.x += p.x; q.y += p.y; q.z += p.z; q.w += p.w;
              }
              v[j] = q.x; v[j + 1] = q.y; v[j + 2] = q.z; v[j + 3] = q.w;
            }
          } else {
            const int row = (MODE == 0) ? tok_list[slot] : slot;
            const float* src = Ain + (size_t)row * INS + kb * 256 + s * 256 + kk * 16;
#pragma unroll
            for (int j = 0; j < 16; j += 4) {
              const float4 q = *(const float4*)(src + j);
              v[j] = q.x; v[j + 1] = q.y; v[j + 2] = q.z; v[j + 3] = q.w;
            }
          }
        } else {
#pragma unroll
          for (int j = 0; j < 16; j++) v[j] = 0.f;
        }
#pragma unroll
        for (int j = 0; j < 16; j++) act_t[(kk * 16 + j) * 32 + tok] = v[j];
      }
      __syncthreads();

      // ---- 256 rows: rotating 8-slot prefetch, distance 4 (static cur/pre: 256%8==0) ----
#pragma unroll 8
      for (int rr = 0; rr < 256; ++rr) {
        const int r   = s * 256 + rr;
        const int cur = rr & 7;
        const int pre = (rr + 4) & 7;
        const int rp  = min(r + 4, KBLK - 1);
        wbuf[pre] = *(const float4*)(Wcol + (size_t)rp * NCT);
        const float4 xv = *(const float4*)(&act_t[rr * 32 + tg * 4]);  // broadcast
        FMA4(acc[0], xv.x, wbuf[cur]);
        FMA4(acc[1], xv.y, wbuf[cur]);
        FMA4(acc[2], xv.z, wbuf[cur]);
        FMA4(acc[3], xv.w, wbuf[cur]);
      }
    }

    // ---- direct store: 4 tokens x 4 cols, static indexing ----
    float4 bv = {0.f, 0.f, 0.f, 0.f};
    if (MODE <= 1) bv = *(const float4*)(Bias + (size_t)e * NCT + col);
#pragma unroll
    for (int tt = 0; tt < 4; tt++) {
      if (tg * 4 + tt < tcn) {
        const int slot = off + tc0 + tg * 4 + tt;
        float4 o = acc[tt];
        if (MODE <= 1) {
          o.x = gelu_f(o.x + bv.x); o.y = gelu_f(o.y + bv.y);
          o.z = gelu_f(o.z + bv.z); o.w = gelu_f(o.w + bv.w);
          *(float4*)(Out + (size_t)slot * NCT + col) = o;
        } else if (MODE == 2) {
          *(float4*)(Out + ((size_t)kb * NSLOT + slot) * DBOT + col) = o;
        } else {
          *(float4*)(Out + (size_t)slot * DOUT + col) = o;
        }
      }
    }
    __syncthreads();   // stores/acc done before next chunk restages act_t
  }
}

// ---------------- combine: y[n] = sum_k w_k * (OutS[slot_k] + bl[e_k]) ----------------
__global__ __launch_bounds__(192) void combine_kernel(
    const float* __restrict__ OutS, const float* __restrict__ bl,
    const int* __restrict__ topk_idx, const float* __restrict__ topk_w,
    const int* __restrict__ tok2slot, float* __restrict__ y) {
  const int n = blockIdx.x;
  const int c = threadIdx.x * 4;
  const int s0 = tok2slot[2 * n], s1 = tok2slot[2 * n + 1];
  const int e0 = topk_idx[2 * n], e1 = topk_idx[2 * n + 1];
  const float w0 = topk_w[2 * n], w1 = topk_w[2 * n + 1];
  const float4 a  = *(const float4*)(OutS + (size_t)s0 * DOUT + c);
  const float4 b  = *(const float4*)(OutS + (size_t)s1 * DOUT + c);
  const float4 ba = *(const float4*)(bl + (size_t)e0 * DOUT + c);
  const float4 bb = *(const float4*)(bl + (size_t)e1 * DOUT + c);
  float4 o;
  o.x = w0 * (a.x + ba.x) + w1 * (b.x + bb.x);
  o.y = w0 * (a.y + ba.y) + w1 * (b.y + bb.y);
  o.z = w0 * (a.z + ba.z) + w1 * (b.z + bb.z);
  o.w = w0 * (a.w + ba.w) + w1 * (b.w + bb.w);
  *(float4*)(y + (size_t)n * DOUT + c) = o;
}

extern "C" void kernel_launch(void* const* d_in, const int* in_sizes, int n_in,
                              void* d_out, int out_size, void* d_ws, size_t ws_size,
                              hipStream_t stream) {
  const float* x  = (const float*)d_in[0];
  const float* gw = (const float*)d_in[1];
  const float* W1 = (const float*)d_in[2];
  const float* b1 = (const float*)d_in[3];
  const float* W2 = (const float*)d_in[4];
  const float* b2 = (const float*)d_in[5];
  const float* W3 = (const float*)d_in[6];
  const float* b3 = (const float*)d_in[7];
  const float* Wl = (const float*)d_in[8];
  const float* bl = (const float*)d_in[9];
  float* y  = (float*)d_out;
  float* ws = (float*)d_ws;

  float* topk_w   = ws;                    // 512 f
  int*   topk_idx = (int*)(ws + 512);      // 512 i
  int*   counts   = (int*)(ws + 1024);     // 32 i
  int*   offsets  = (int*)(ws + 1056);     // 32 i
  int*   tok_list = (int*)(ws + 1088);     // 512 i
  int*   tok2slot = (int*)(ws + 1600);     // 512 i
  float* B1    = ws + 4096;                        // 512*2048
  float* B2    = B1 + (size_t)NSLOT * DHID;        // 512*2048
  float* zpart = B2 + (size_t)NSLOT * DHID;        // 8*512*256
  float* OutS  = zpart + (size_t)8 * NSLOT * DBOT; // 512*768

  gate_kernel<<<NTOK, 64, 0, stream>>>(x, gw, topk_idx, topk_w);
  build_lists<<<1, 256, 0, stream>>>(topk_idx, counts, offsets, tok_list, tok2slot);
  // L1: B1 = gelu(x @ W1 + b1)        (8 coltiles x 32 experts = 256 blocks, K=768)
  ff_kernel<0><<<dim3(8, 32), 512, 0, stream>>>(x,  W1, b1, B1, nullptr,
                                                offsets, counts, tok_list);
  // L2: B2 = gelu(B1 @ W2 + b2)       (8 coltiles x 32 experts = 256 blocks, K=2048)
  ff_kernel<1><<<dim3(8, 32), 512, 0, stream>>>(B1, W2, b2, B2, nullptr,
                                                offsets, counts, tok_list);
  // L3: zpart[kb] = B2 @ W3 slice     (8 K-slices x 32 experts = 256 blocks)
  ff_kernel<2><<<dim3(8, 32), 512, 0, stream>>>(B2, W3, nullptr, zpart, nullptr,
                                                offsets, counts, tok_list);
  // L4: OutS = (sum zpart + b3) @ Wl  (3 coltiles x 32 experts = 96 blocks)
  ff_kernel<3><<<dim3(3, 32), 512, 0, stream>>>(nullptr, Wl, b3, OutS, zpart,
                                                offsets, counts, tok_list);
  // combine: y = sum_k w_k (OutS + bl)
  combine_kernel<<<NTOK, 192, 0, stream>>>(OutS, bl, topk_idx, topk_w, tok2slot, y);
}

// Round 13
// 401.363 us; speedup vs baseline: 1.9032x; 1.1085x over previous
//
#include <hip/hip_runtime.h>
#include <math.h>

#define NEXP 32
#define NTOK 256
#define DIMD 768
#define DHID 2048
#define DBOT 256
#define DOUT 768
#define NSLOT 512

// ---------------- gate: logits -> top2 -> normalized weights ----------------
__global__ __launch_bounds__(64) void gate_kernel(
    const float* __restrict__ x, const float* __restrict__ gw,
    int* __restrict__ topk_idx, float* __restrict__ topk_w) {
  const int n = blockIdx.x;
  const int l = threadIdx.x;
  const float* xr = x + n * DIMD;
  float xs[12];
#pragma unroll
  for (int j = 0; j < 12; j++) xs[j] = xr[l + 64 * j];
  float logit[NEXP];
#pragma unroll
  for (int e = 0; e < NEXP; e++) {
    const float* g = gw + e * DIMD;
    float p = 0.f;
#pragma unroll
    for (int j = 0; j < 12; j++) p = fmaf(xs[j], g[l + 64 * j], p);
#pragma unroll
    for (int m = 1; m < 64; m <<= 1) p += __shfl_xor(p, m);
    logit[e] = p;
  }
  int i0 = 0; float m0 = logit[0];
#pragma unroll
  for (int e = 1; e < NEXP; e++) { if (logit[e] > m0) { m0 = logit[e]; i0 = e; } }
  int i1 = -1; float m1 = -3.4e38f;
#pragma unroll
  for (int e = 0; e < NEXP; e++) { if (e != i0 && logit[e] > m1) { m1 = logit[e]; i1 = e; } }
  const float e1 = expf(m1 - m0);
  const float w0 = 1.f / (1.f + e1);
  const float w1 = e1 * w0;
  if (l == 0) {
    topk_idx[2 * n] = i0; topk_idx[2 * n + 1] = i1;
    topk_w[2 * n] = w0;  topk_w[2 * n + 1] = w1;
  }
}

// ---------------- build per-expert token lists + maps ----------------
__global__ __launch_bounds__(256) void build_lists(
    const int* __restrict__ topk_idx,
    int* __restrict__ counts, int* __restrict__ offsets,
    int* __restrict__ tok_list, int* __restrict__ tok2slot,
    int* __restrict__ slot_expert) {
  __shared__ int cnt[NEXP], base[NEXP], fill[NEXP];
  const int t = threadIdx.x;
  if (t < NEXP) { cnt[t] = 0; fill[t] = 0; }
  __syncthreads();
  const int e0 = topk_idx[2 * t], e1 = topk_idx[2 * t + 1];
  atomicAdd(&cnt[e0], 1);
  atomicAdd(&cnt[e1], 1);
  __syncthreads();
  if (t == 0) { int s = 0; for (int i = 0; i < NEXP; i++) { base[i] = s; s += cnt[i]; } }
  __syncthreads();
  const int p0 = atomicAdd(&fill[e0], 1);
  tok_list[base[e0] + p0] = t; tok2slot[2 * t] = base[e0] + p0;
  slot_expert[base[e0] + p0] = e0;
  const int p1 = atomicAdd(&fill[e1], 1);
  tok_list[base[e1] + p1] = t; tok2slot[2 * t + 1] = base[e1] + p1;
  slot_expert[base[e1] + p1] = e1;
  if (t < NEXP) { counts[t] = cnt[t]; offsets[t] = base[t]; }
}

__device__ __forceinline__ float gelu_f(float v) {
  return 0.5f * v * (1.f + erff(v * 0.70710678118654752f));
}

// ---------------- zsum: zsum[slot] = sum_k zpart[k][slot] + b3[e(slot)] ----------------
__global__ __launch_bounds__(64) void zsum_kernel(
    const float* __restrict__ zpart, const float* __restrict__ b3,
    const int* __restrict__ slot_expert, float* __restrict__ zsum) {
  const int slot = blockIdx.x;
  const int c = threadIdx.x * 4;
  const int e = slot_expert[slot];
  float4 q = *(const float4*)(b3 + (size_t)e * DBOT + c);
#pragma unroll
  for (int k = 0; k < 8; k++) {
    const float4 p = *(const float4*)(zpart + ((size_t)k * NSLOT + slot) * DBOT + c);
    q.x += p.x; q.y += p.y; q.z += p.z; q.w += p.w;
  }
  *(float4*)(zsum + (size_t)slot * DBOT + c) = q;
}

#define FMA4(A, XS, WV) \
  A.x = fmaf(XS, WV.x, A.x); A.y = fmaf(XS, WV.y, A.y); \
  A.z = fmaf(XS, WV.z, A.z); A.w = fmaf(XS, WV.w, A.w)

// ---------------- expert FF layer: WEIGHTS stream through LDS (global_load_lds) ----
// Block 512 thr = 8 waves; 256-col tile; wave tg owns tokens tg*4..+3; lane owns 4 cols.
// Per 64-row section: stage W-tile 64x256 (64 KB) via 8 gload_lds calls/thread-wave
// (fire-and-forget queue -> ~64 KB/CU in flight, covers HBM latency; the per-VGPR
// prefetch of R7-R12 capped at ~4 KB/CU -> 1.3 TB/s, R11 counters).
// Act staged T14-style: issue float4 early, ds_write late. Double-buffered, 1 barrier/section.
// Per row/thread: 1 distinct b128 (W) + 1 broadcast b128 (act) + 16 FMA.
// LDS ~4.8k cy < HBM fair-share 6.2k cy per section -> HBM-bound.
// MODE 0: B1 = gelu(x(gather) @ W1 + b1)   grid (8,32)  K=768
// MODE 1: B2 = gelu(B1 @ W2 + b2)          grid (8,32)  K=2048
// MODE 2: zpart[kb] = B2 @ W3 K-slice      grid (8,32)  K=256/block
// MODE 3: OutS = zsum @ Wl                 grid (3,32)  K=256
template <int MODE>
__global__ __launch_bounds__(512, 2) void ff_kernel(
    const float* __restrict__ Ain, const float* __restrict__ W,
    const float* __restrict__ Bias, float* __restrict__ Out,
    const int* __restrict__ offsets, const int* __restrict__ counts,
    const int* __restrict__ tok_list) {
  constexpr int NCT   = (MODE <= 1) ? 2048 : (MODE == 2) ? 256 : 768;
  constexpr int KFULL = (MODE == 0) ? 768 : (MODE == 3) ? 256 : 2048;
  constexpr int INS   = (MODE == 0) ? DIMD : (MODE == 3) ? DBOT : DHID;
  constexpr int NSEC  = (MODE == 0) ? 12 : (MODE == 1) ? 32 : 4;
  __shared__ float Wlds[2 * 64 * 256];   // 128 KB double-buffered weight tile
  __shared__ float act_t[2 * 64 * 32];   // 16 KB double-buffered act (transposed)
  const int tid  = threadIdx.x;
  const int lane = tid & 63;
  const int wave = tid >> 6;
  const int tg   = wave;               // token group (4 tokens)
  const int e    = blockIdx.y;
  const int kb   = (MODE == 2) ? blockIdx.x : 0;
  const int ct   = (MODE == 2) ? 0 : blockIdx.x;
  const int kbase = kb * 256;
  const int cnt = counts[e];
  const int off = offsets[e];
  const int col = ct * 256 + lane * 4;
  const float* Wsrc = W + ((size_t)e * KFULL) * NCT + (size_t)ct * 256;
  const int tok = tid & 31;
  const int kk  = tid >> 5;            // 0..15, stages rows kk*4..+3

  for (int tc0 = 0; tc0 < cnt; tc0 += 32) {
    const int tcn = min(32, cnt - tc0);
    const int slot = off + tc0 + tok;
    const float* Arow = nullptr;
    if (tok < tcn) {
      const int row = (MODE == 0) ? tok_list[slot] : slot;
      Arow = Ain + (size_t)row * INS + kbase;
    }

    float4 acc[4];
#pragma unroll
    for (int t = 0; t < 4; t++) acc[t] = {0.f, 0.f, 0.f, 0.f};
    float4 av = {0.f, 0.f, 0.f, 0.f};

    // ---- staging helpers ----
    auto a_issue = [&](int s) {           // issue act float4 (early)
      if (Arow) av = *(const float4*)(Arow + s * 64 + kk * 4);
      else      av = {0.f, 0.f, 0.f, 0.f};
    };
    auto w_issue = [&](int b, int s) {    // 8 gload_lds calls: wave stages 8 rows
      float* wl = Wlds + b * 16384;
      const float* src = Wsrc + (size_t)(kbase + s * 64) * NCT;
#pragma unroll
      for (int c = 0; c < 8; c++) {
        const int r = c * 8 + wave;
        __builtin_amdgcn_global_load_lds(
            (const __attribute__((address_space(1))) void*)(src + (size_t)r * NCT + lane * 4),
            (__attribute__((address_space(3))) void*)(wl + r * 256),
            16, 0, 0);
      }
    };
    auto a_write = [&](int b) {           // ds_write act (late)
      float* at = act_t + b * 2048;
      at[(kk * 4 + 0) * 32 + tok] = av.x;
      at[(kk * 4 + 1) * 32 + tok] = av.y;
      at[(kk * 4 + 2) * 32 + tok] = av.z;
      at[(kk * 4 + 3) * 32 + tok] = av.w;
    };

    // ---- prologue: stage section 0 ----
    a_issue(0);
    w_issue(0, 0);
    a_write(0);
    __syncthreads();   // drains gload_lds (vmcnt) + ds_writes

    // ---- section loop ----
    for (int s = 0; s < NSEC; s++) {
      const int b = s & 1;
      if (s + 1 < NSEC) {
        a_issue(s + 1);        // act loads first (waited by a_write's vmcnt(8))
        w_issue(b ^ 1, s + 1); // weight stages fly through the whole compute below
      }
      {  // ---- compute section s ----
        const float* wl = Wlds + b * 16384 + lane * 4;
        const float* at = act_t + b * 2048 + tg * 4;
#pragma unroll 8
        for (int r = 0; r < 64; r++) {
          const float4 wv = *(const float4*)(wl + r * 256);
          const float4 xv = *(const float4*)(at + r * 32);   // wave-uniform broadcast
          FMA4(acc[0], xv.x, wv);
          FMA4(acc[1], xv.y, wv);
          FMA4(acc[2], xv.z, wv);
          FMA4(acc[3], xv.w, wv);
        }
      }
      if (s + 1 < NSEC) a_write(b ^ 1);
      __syncthreads();
    }

    // ---- epilogue: direct stores (no atomics) ----
    float4 bv = {0.f, 0.f, 0.f, 0.f};
    if (MODE <= 1) bv = *(const float4*)(Bias + (size_t)e * NCT + col);
#pragma unroll
    for (int tt = 0; tt < 4; tt++) {
      if (tg * 4 + tt < tcn) {
        const int os = off + tc0 + tg * 4 + tt;
        float4 o = acc[tt];
        if (MODE <= 1) {
          o.x = gelu_f(o.x + bv.x); o.y = gelu_f(o.y + bv.y);
          o.z = gelu_f(o.z + bv.z); o.w = gelu_f(o.w + bv.w);
          *(float4*)(Out + (size_t)os * NCT + col) = o;
        } else if (MODE == 2) {
          *(float4*)(Out + ((size_t)kb * NSLOT + os) * DBOT + col) = o;
        } else {
          *(float4*)(Out + (size_t)os * DOUT + col) = o;
        }
      }
    }
    __syncthreads();   // buffers free before next chunk
  }
}

// ---------------- combine: y[n] = sum_k w_k * (OutS[slot_k] + bl[e_k]) ----------------
__global__ __launch_bounds__(192) void combine_kernel(
    const float* __restrict__ OutS, const float* __restrict__ bl,
    const int* __restrict__ topk_idx, const float* __restrict__ topk_w,
    const int* __restrict__ tok2slot, float* __restrict__ y) {
  const int n = blockIdx.x;
  const int c = threadIdx.x * 4;
  const int s0 = tok2slot[2 * n], s1 = tok2slot[2 * n + 1];
  const int e0 = topk_idx[2 * n], e1 = topk_idx[2 * n + 1];
  const float w0 = topk_w[2 * n], w1 = topk_w[2 * n + 1];
  const float4 a  = *(const float4*)(OutS + (size_t)s0 * DOUT + c);
  const float4 b  = *(const float4*)(OutS + (size_t)s1 * DOUT + c);
  const float4 ba = *(const float4*)(bl + (size_t)e0 * DOUT + c);
  const float4 bb = *(const float4*)(bl + (size_t)e1 * DOUT + c);
  float4 o;
  o.x = w0 * (a.x + ba.x) + w1 * (b.x + bb.x);
  o.y = w0 * (a.y + ba.y) + w1 * (b.y + bb.y);
  o.z = w0 * (a.z + ba.z) + w1 * (b.z + bb.z);
  o.w = w0 * (a.w + ba.w) + w1 * (b.w + bb.w);
  *(float4*)(y + (size_t)n * DOUT + c) = o;
}

extern "C" void kernel_launch(void* const* d_in, const int* in_sizes, int n_in,
                              void* d_out, int out_size, void* d_ws, size_t ws_size,
                              hipStream_t stream) {
  const float* x  = (const float*)d_in[0];
  const float* gw = (const float*)d_in[1];
  const float* W1 = (const float*)d_in[2];
  const float* b1 = (const float*)d_in[3];
  const float* W2 = (const float*)d_in[4];
  const float* b2 = (const float*)d_in[5];
  const float* W3 = (const float*)d_in[6];
  const float* b3 = (const float*)d_in[7];
  const float* Wl = (const float*)d_in[8];
  const float* bl = (const float*)d_in[9];
  float* y  = (float*)d_out;
  float* ws = (float*)d_ws;

  float* topk_w   = ws;                    // 512 f
  int*   topk_idx = (int*)(ws + 512);      // 512 i
  int*   counts   = (int*)(ws + 1024);     // 32 i
  int*   offsets  = (int*)(ws + 1056);     // 32 i
  int*   tok_list = (int*)(ws + 1088);     // 512 i
  int*   tok2slot = (int*)(ws + 1600);     // 512 i
  int*   slot_exp = (int*)(ws + 2112);     // 512 i
  float* B1    = ws + 4096;                        // 512*2048
  float* B2    = B1 + (size_t)NSLOT * DHID;        // 512*2048
  float* zpart = B2 + (size_t)NSLOT * DHID;        // 8*512*256
  float* zsum  = zpart + (size_t)8 * NSLOT * DBOT; // 512*256
  float* OutS  = zsum + (size_t)NSLOT * DBOT;      // 512*768

  gate_kernel<<<NTOK, 64, 0, stream>>>(x, gw, topk_idx, topk_w);
  build_lists<<<1, 256, 0, stream>>>(topk_idx, counts, offsets, tok_list, tok2slot, slot_exp);
  // L1: B1 = gelu(x @ W1 + b1)        (8 coltiles x 32 experts, K=768)
  ff_kernel<0><<<dim3(8, 32), 512, 0, stream>>>(x,  W1, b1, B1, offsets, counts, tok_list);
  // L2: B2 = gelu(B1 @ W2 + b2)       (8 coltiles x 32 experts, K=2048)
  ff_kernel<1><<<dim3(8, 32), 512, 0, stream>>>(B1, W2, b2, B2, offsets, counts, tok_list);
  // L3: zpart[kb] = B2 @ W3 slice     (8 K-slices x 32 experts)
  ff_kernel<2><<<dim3(8, 32), 512, 0, stream>>>(B2, W3, nullptr, zpart, offsets, counts, tok_list);
  // zsum = sum zpart + b3
  zsum_kernel<<<NSLOT, 64, 0, stream>>>(zpart, b3, slot_exp, zsum);
  // L4: OutS = zsum @ Wl              (3 coltiles x 32 experts, K=256)
  ff_kernel<3><<<dim3(3, 32), 512, 0, stream>>>(zsum, Wl, nullptr, OutS, offsets, counts, tok_list);
  // combine: y = sum_k w_k (OutS + bl)
  combine_kernel<<<NTOK, 192, 0, stream>>>(OutS, bl, topk_idx, topk_w, tok2slot, y);
}